// Round 17
// baseline (93.864 us; speedup 1.0000x reference)
//
#include <hip/hip_runtime.h>
#include <hip/hip_bf16.h>
#include <math.h>

// BahdanauAttention: B=32, T=2048, D=512, U=512, fp32 in/out.
#define BB 32
#define TT 2048
#define DD 512
#define UU 512

typedef __attribute__((ext_vector_type(8))) short short8v;     // MFMA bf16 A/B frag
typedef __attribute__((ext_vector_type(4))) float floatx4;     // MFMA C/D frag
typedef __attribute__((ext_vector_type(8))) unsigned short ushort8v;
typedef __attribute__((ext_vector_type(4))) unsigned short ushort4v;

static __device__ inline unsigned short f2bf(float f) {
  __hip_bfloat16 h = __float2bfloat16(f);
  return *reinterpret_cast<unsigned short*>(&h);
}

static __device__ inline float fast_tanh(float x) {
  x = fminf(fmaxf(x, -15.f), 15.f);
  float e2 = __expf(2.f * x);
  return (e2 - 1.f) * __builtin_amdgcn_rcpf(e2 + 1.f);
}

// ---------------------------------------------------------------------------
// K0: W1[k][u] fp32 -> w1a blocked bf16 [kt(16)][kg(4)][u(512)][8]
// (layout verified r7-r16). grid (16 kt, 4 uc), block 256.
// ---------------------------------------------------------------------------
__global__ __launch_bounds__(256) void pack_w1a_kernel(
    const float* __restrict__ W1, unsigned short* __restrict__ w1a) {
  __shared__ float Wf[32][132];
  const int kt = blockIdx.x, uc = blockIdx.y;
  const int tid = threadIdx.x;
  {
    const int k = tid >> 3;
    const int u16 = (tid & 7) * 16;
    const float* src = W1 + (size_t)(kt * 32 + k) * UU + uc * 128 + u16;
    #pragma unroll
    for (int q = 0; q < 4; ++q) {
      const float4 v = *(const float4*)(src + q * 4);
      Wf[k][u16 + q * 4 + 0] = v.x;
      Wf[k][u16 + q * 4 + 1] = v.y;
      Wf[k][u16 + q * 4 + 2] = v.z;
      Wf[k][u16 + q * 4 + 3] = v.w;
    }
  }
  __syncthreads();
  unsigned short* dst = w1a + (size_t)kt * 16384;  // 32 KB per kt
  #pragma unroll
  for (int s = 0; s < 2; ++s) {
    const int c = s * 256 + tid;
    const int kg = c >> 7;
    const int u = c & 127;
    ushort8v o;
    #pragma unroll
    for (int e = 0; e < 8; ++e) o[e] = f2bf(Wf[kg * 8 + e][u]);
    *(ushort8v*)(dst + ((size_t)kg * 512 + uc * 128 + u) * 8) = o;
  }
}

// ---------------------------------------------------------------------------
// K1: qb[b,u] = query[b,:] @ W2[:,u] + b2[u] + b1[u]
// ---------------------------------------------------------------------------
__global__ __launch_bounds__(256) void projq_kernel(
    const float* __restrict__ query, const float* __restrict__ W2,
    const float* __restrict__ b2, const float* __restrict__ b1,
    float* __restrict__ qb) {
  int b = blockIdx.x;
  int u = blockIdx.y * 256 + threadIdx.x;
  float acc = b2[u] + b1[u];
  const float* q = query + b * DD;
  #pragma unroll 16
  for (int d = 0; d < DD; ++d) acc += q[d] * W2[(size_t)d * UU + u];
  qb[b * UU + u] = acc;
}

// ---------------------------------------------------------------------------
// K2: FUSED score+context kernel, SBM=128 (2x MFMA per wave-step vs r16).
// Block = 128 rows x 512u, 8 waves; wave = 64u x 128m; acc 4x8 frags.
// Full B panel (128 rows x 512k bf16 = 128KB) staged ONCE; barrier-free
// K-loop (r11 class): A dist-1 reg prefetch from L2-hot w1a, B from LDS.
// Tail: no-max-shift softmax partials (r16, verified).
// LDS ~145KB -> 1 block/CU; __launch_bounds__(512,2).
// ---------------------------------------------------------------------------
#define SBM 128

__global__ __launch_bounds__(512, 2) void score_fused_kernel(
    const float* __restrict__ values, const unsigned short* __restrict__ w1a,
    const float* __restrict__ qb, const float* __restrict__ V,
    float* __restrict__ score, float* __restrict__ o_part,
    float* __restrict__ l_part) {
  __shared__ __align__(16) unsigned short Bp[16][4][SBM][8];  // 128 KB [kt][kg][m][8]
  __shared__ float qv_lds[512];
  __shared__ float vv_lds[512];
  __shared__ float part[8][SBM];   // 4 KB
  __shared__ float sw[SBM];
  __shared__ float opart[4][512];  // 8 KB

  const int tid = threadIdx.x;
  const int row0 = blockIdx.x * SBM;
  const int b = row0 >> 11;           // row0 / TT (128 divides 2048)
  const int lane = tid & 63;
  const int wid = tid >> 6;           // 8 waves -> u slice
  const int wu = wid * 64;
  const int fr = lane & 15;
  const int kg = lane >> 4;

  qv_lds[tid] = qb[b * UU + tid];     // b1,b2 folded into qb
  vv_lds[tid] = V[tid];

  // ---- stage the WHOLE B panel once: 128 rows x 512 k, fp32 -> bf16 ----
  // thread = (row sm = tid>>2, lane-quad sj = tid&3); 32 float4s in 4 batches.
  {
    const int sm = tid >> 2;
    const int sj = tid & 3;
    const float* bsrc = values + (size_t)(row0 + sm) * DD + sj * 4;
    #pragma unroll
    for (int batch = 0; batch < 4; ++batch) {
      float4 r[8];
      #pragma unroll
      for (int i = 0; i < 8; ++i)
        r[i] = *(const float4*)(bsrc + (size_t)(batch * 8 + i) * 16);
      #pragma unroll
      for (int i = 0; i < 8; ++i) {
        const int f = sj * 4 + (batch * 8 + i) * 16;  // float offset in row
        const int kt = f >> 5;
        const int kgw = (f >> 3) & 3;
        const int e = f & 7;  // 0 or 4
        ushort4v o = {f2bf(r[i].x), f2bf(r[i].y), f2bf(r[i].z), f2bf(r[i].w)};
        *(ushort4v*)&Bp[kt][kgw][sm][e] = o;
      }
    }
  }

  // ---- A-frag double buffer (dist-1), prologue A(0) ----
  const size_t aofs = (size_t)(kg * 512 + wu + fr) * 8;
  short8v af[2][4];
  #pragma unroll
  for (int ju = 0; ju < 4; ++ju)
    af[0][ju] = *(const short8v*)(w1a + aofs + (size_t)ju * 128);

  __syncthreads();  // panel + preloads visible; only pre-epilogue barrier

  floatx4 acc[4][8] = {};  // [ju][jm] = 128 VGPR

  #pragma unroll
  for (int t = 0; t < 16; ++t) {
    const int cur = t & 1;
    if (t + 1 < 16) {  // prefetch next A frags (L2-hot, per-wave-private)
      #pragma unroll
      for (int ju = 0; ju < 4; ++ju)
        af[cur ^ 1][ju] =
            *(const short8v*)(w1a + (size_t)(t + 1) * 16384 + aofs + (size_t)ju * 128);
    }
    #pragma unroll
    for (int jm = 0; jm < 8; ++jm) {
      const short8v bfv = *(const short8v*)&Bp[t][kg][jm * 16 + fr][0];
      #pragma unroll
      for (int ju = 0; ju < 4; ++ju)
        acc[ju][jm] = __builtin_amdgcn_mfma_f32_16x16x32_bf16(af[cur][ju], bfv, acc[ju][jm], 0, 0, 0);
    }
  }

  // ---- GEMM epilogue: tanh + V-weight; u on the register axis ----
  // C[u][m]: m = jm*16 + fr, u = wu + ju*16 + kg*4 + reg  [verified r7-r16]
  float pm[8] = {};
  #pragma unroll
  for (int ju = 0; ju < 4; ++ju) {
    const float4 qv = *(const float4*)&qv_lds[wu + ju * 16 + kg * 4];
    const float4 vv = *(const float4*)&vv_lds[wu + ju * 16 + kg * 4];
    const float qa[4] = {qv.x, qv.y, qv.z, qv.w};
    const float va[4] = {vv.x, vv.y, vv.z, vv.w};
    #pragma unroll
    for (int jm = 0; jm < 8; ++jm)
      #pragma unroll
      for (int reg = 0; reg < 4; ++reg)
        pm[jm] += fast_tanh(acc[ju][jm][reg] + qa[reg]) * va[reg];
  }
  #pragma unroll
  for (int jm = 0; jm < 8; ++jm) {
    pm[jm] += __shfl_xor(pm[jm], 16, 64);
    pm[jm] += __shfl_xor(pm[jm], 32, 64);
  }
  if (lane < 16) {
    #pragma unroll
    for (int jm = 0; jm < 8; ++jm) part[wid][jm * 16 + lane] = pm[jm];
  }
  __syncthreads();  // part visible
  if (tid < SBM) {
    float s = 0.f;
    #pragma unroll
    for (int w = 0; w < 8; ++w) s += part[w][tid];
    score[row0 + tid] = s;
    sw[tid] = __expf(s);   // no max-shift: |s| <= ~18, fp32-safe (r16-verified)
  }
  __syncthreads();  // sw visible

  // ---- fused context partial: o = sum_r exp(s_r) * values[r][:] ----
  // group g = tid>>7 (0..3) -> rows g*32..g*32+31; dq = tid&127 -> d = dq*4.
  {
    const int g = tid >> 7;
    const int dq = tid & 127;
    const float* vrow = values + (size_t)(row0 + g * 32) * DD + dq * 4;
    float4 o4 = {0.f, 0.f, 0.f, 0.f};
    #pragma unroll 8
    for (int r = 0; r < 32; ++r) {
      const float w = sw[g * 32 + r];
      const float4 v = *(const float4*)(vrow + (size_t)r * DD);  // L2-hot
      o4.x += w * v.x; o4.y += w * v.y; o4.z += w * v.z; o4.w += w * v.w;
    }
    *(float4*)&opart[g][dq * 4] = o4;
  }
  if (wid == 0) {  // wave 0: l = sum of the 128 exp(s)
    float lv = sw[lane] + sw[lane + 64];
    #pragma unroll
    for (int m = 1; m < 64; m <<= 1) lv += __shfl_xor(lv, m, 64);
    if (lane == 0) l_part[blockIdx.x] = lv;
  }
  __syncthreads();  // opart visible
  {
    const int d = tid;  // 512 threads = 512 d
    o_part[(size_t)blockIdx.x * DD + d] =
        opart[0][d] + opart[1][d] + opart[2][d] + opart[3][d];
  }
}

// ---------------------------------------------------------------------------
// K3: reduce per-chunk partials -> ctx and Linv. 16 chunks per batch now.
// grid (32 b), block 128.
// ---------------------------------------------------------------------------
__global__ __launch_bounds__(128) void reduce_kernel(
    const float* __restrict__ o_part, const float* __restrict__ l_part,
    float* __restrict__ ctx, float* __restrict__ Linv) {
  const int b = blockIdx.x;
  const int d0 = threadIdx.x * 4;
  __shared__ float Ls;
  if (threadIdx.x == 0) {
    float s = 0.f;
    #pragma unroll
    for (int c = 0; c < 16; ++c) s += l_part[b * 16 + c];
    Ls = 1.f / s;
    Linv[b] = Ls;
  }
  float4 a = {0.f, 0.f, 0.f, 0.f};
  #pragma unroll
  for (int c = 0; c < 16; ++c) {
    const float4 p = *(const float4*)(o_part + (size_t)(b * 16 + c) * DD + d0);
    a.x += p.x; a.y += p.y; a.z += p.z; a.w += p.w;
  }
  __syncthreads();
  const float inv = Ls;
  a.x *= inv; a.y *= inv; a.z *= inv; a.w *= inv;
  *(float4*)(ctx + (size_t)b * DD + d0) = a;
}

// ---------------------------------------------------------------------------
// K4: attn[b,t] = exp(score[b,t]) * Linv[b]. grid 64, block 1024.
// ---------------------------------------------------------------------------
__global__ __launch_bounds__(1024) void attn_kernel(
    const float* __restrict__ score, const float* __restrict__ Linv,
    float* __restrict__ attn) {
  const int i = blockIdx.x * 1024 + threadIdx.x;
  const int b = i >> 11;
  attn[i] = __expf(score[i]) * Linv[b];
}

// ---------------------------------------------------------------------------
extern "C" void kernel_launch(void* const* d_in, const int* in_sizes, int n_in,
                              void* d_out, int out_size, void* d_ws, size_t ws_size,
                              hipStream_t stream) {
  const float* query  = (const float*)d_in[0];
  const float* values = (const float*)d_in[1];
  const float* W1     = (const float*)d_in[2];
  const float* b1     = (const float*)d_in[3];
  const float* W2     = (const float*)d_in[4];
  const float* b2     = (const float*)d_in[5];
  const float* V      = (const float*)d_in[6];
  // d_in[7] = bV: uniform score shift -> softmax-invariant, dropped.

  float* ctx  = (float*)d_out;             // [B,D]
  float* attn = (float*)d_out + BB * DD;   // [B,T,1]

  // ws: qb 64KB | score 256KB | w1a 512KB | o_part 1MB | l_part | Linv
  float* qb           = (float*)d_ws;                        // [B,U]
  float* score        = qb + BB * UU;                        // [B*T]
  unsigned short* w1a = (unsigned short*)(score + BB * TT);  // 512KB bf16
  float* o_part       = (float*)(w1a + (size_t)UU * DD);     // [512][512]
  float* l_part       = o_part + (size_t)512 * DD;           // [512]
  float* Linv         = l_part + 512;                        // [32]

  pack_w1a_kernel<<<dim3(16, 4), 256, 0, stream>>>(W1, w1a);
  projq_kernel<<<dim3(BB, UU / 256), 256, 0, stream>>>(query, W2, b2, b1, qb);

  score_fused_kernel<<<(BB * TT) / SBM, 512, 0, stream>>>(
      values, w1a, qb, V, score, o_part, l_part);

  reduce_kernel<<<BB, 128, 0, stream>>>(o_part, l_part, ctx, Linv);
  attn_kernel<<<(BB * TT) / 1024, 1024, 0, stream>>>(score, Linv, attn);
}

// Round 18
// 88.776 us; speedup vs baseline: 1.0573x; 1.0573x over previous
//
#include <hip/hip_runtime.h>
#include <hip/hip_bf16.h>
#include <math.h>

// BahdanauAttention: B=32, T=2048, D=512, U=512, fp32 in/out.
#define BB 32
#define TT 2048
#define DD 512
#define UU 512

typedef __attribute__((ext_vector_type(8))) short short8v;     // MFMA bf16 A/B frag
typedef __attribute__((ext_vector_type(4))) float floatx4;     // MFMA C/D frag
typedef __attribute__((ext_vector_type(8))) unsigned short ushort8v;
typedef __attribute__((ext_vector_type(4))) unsigned short ushort4v;

static __device__ inline unsigned short f2bf(float f) {
  __hip_bfloat16 h = __float2bfloat16(f);
  return *reinterpret_cast<unsigned short*>(&h);
}

static __device__ inline float fast_tanh(float x) {
  x = fminf(fmaxf(x, -15.f), 15.f);
  float e2 = __expf(2.f * x);
  return (e2 - 1.f) * __builtin_amdgcn_rcpf(e2 + 1.f);
}

// No-drain step sync: make OUR ds_writes visible, cross the barrier, but
// leave global loads in flight (no vmcnt wait). sched_barrier(0) pins the
// compiler (rule #18: inline-asm waitcnt is not an ordering fence by itself).
static __device__ inline void step_sync() {
  __builtin_amdgcn_sched_barrier(0);
  asm volatile("s_waitcnt lgkmcnt(0)" ::: "memory");
  __builtin_amdgcn_sched_barrier(0);
  __builtin_amdgcn_s_barrier();
  __builtin_amdgcn_sched_barrier(0);
}

// ---------------------------------------------------------------------------
// K0: W1[k][u] fp32 -> w1a blocked bf16 [kt(16)][kg(4)][u(512)][8]
// (layout verified r7-r17). grid (16 kt, 4 uc), block 256.
// ---------------------------------------------------------------------------
__global__ __launch_bounds__(256) void pack_w1a_kernel(
    const float* __restrict__ W1, unsigned short* __restrict__ w1a) {
  __shared__ float Wf[32][132];
  const int kt = blockIdx.x, uc = blockIdx.y;
  const int tid = threadIdx.x;
  {
    const int k = tid >> 3;
    const int u16 = (tid & 7) * 16;
    const float* src = W1 + (size_t)(kt * 32 + k) * UU + uc * 128 + u16;
    #pragma unroll
    for (int q = 0; q < 4; ++q) {
      const float4 v = *(const float4*)(src + q * 4);
      Wf[k][u16 + q * 4 + 0] = v.x;
      Wf[k][u16 + q * 4 + 1] = v.y;
      Wf[k][u16 + q * 4 + 2] = v.z;
      Wf[k][u16 + q * 4 + 3] = v.w;
    }
  }
  __syncthreads();
  unsigned short* dst = w1a + (size_t)kt * 16384;  // 32 KB per kt
  #pragma unroll
  for (int s = 0; s < 2; ++s) {
    const int c = s * 256 + tid;
    const int kg = c >> 7;
    const int u = c & 127;
    ushort8v o;
    #pragma unroll
    for (int e = 0; e < 8; ++e) o[e] = f2bf(Wf[kg * 8 + e][u]);
    *(ushort8v*)(dst + ((size_t)kg * 512 + uc * 128 + u) * 8) = o;
  }
}

// ---------------------------------------------------------------------------
// K1: qb[b,u] = query[b,:] @ W2[:,u] + b2[u] + b1[u]
// ---------------------------------------------------------------------------
__global__ __launch_bounds__(256) void projq_kernel(
    const float* __restrict__ query, const float* __restrict__ W2,
    const float* __restrict__ b2, const float* __restrict__ b1,
    float* __restrict__ qb) {
  int b = blockIdx.x;
  int u = blockIdx.y * 256 + threadIdx.x;
  float acc = b2[u] + b1[u];
  const float* q = query + b * DD;
  #pragma unroll 16
  for (int d = 0; d < DD; ++d) acc += q[d] * W2[(size_t)d * UU + u];
  qb[b * UU + u] = acc;
}

// ---------------------------------------------------------------------------
// K2: FUSED score+context kernel — no-drain barriers + tiny LDS (22.5 KB).
// Block = 64 rows x 512u, 8 waves (wave = 64u x 64m, acc 4x4).
// B (values): per-kt 4KB slab, LDS 2-slot dbuf; 3-deep REG ring of plain
//   float4 loads (load slab t+3 at step t; cvt+write slab t+1 from a load
//   issued 2 full steps earlier -> HBM latency spans 2 steps, never drained).
// A (w1a, L2-hot): dist-2 ring-3 reg prefetch (r12-proven).
// Step sync = lgkmcnt(0) + raw s_barrier (NO vmcnt drain).
// Tail: r16's no-max-shift fused softmax/context partials (verified).
// ---------------------------------------------------------------------------
#define SBM 64

__global__ __launch_bounds__(512, 4) void score_fused_kernel(
    const float* __restrict__ values, const unsigned short* __restrict__ w1a,
    const float* __restrict__ qb, const float* __restrict__ V,
    float* __restrict__ score, float* __restrict__ o_part,
    float* __restrict__ l_part) {
  __shared__ __align__(16) unsigned short Bs[2][4][SBM][8];  // 2 x 4 KB [kg][m][8]
  __shared__ float qv_lds[512];
  __shared__ float vv_lds[512];
  __shared__ float part[8][SBM];   // 2 KB
  __shared__ float sw[SBM];
  __shared__ float opart[4][512];  // 8 KB

  const int tid = threadIdx.x;
  const int row0 = blockIdx.x * SBM;
  const int b = row0 >> 11;           // row0 / TT
  const int lane = tid & 63;
  const int wid = tid >> 6;           // 8 waves -> u slice
  const int wu = wid * 64;
  const int fr = lane & 15;
  const int kg = lane >> 4;

  qv_lds[tid] = qb[b * UU + tid];     // b1,b2 folded into qb
  vv_lds[tid] = V[tid];

  // B staging coords (r10): thread -> (row sm, k-quad sj); 8B ds_write each
  const int sm = tid >> 3;
  const int sj = tid & 7;
  const float* bsrc = values + (size_t)(row0 + sm) * DD + sj * 4;
  const int bofs = (sj >> 1) * (SBM * 8) + sm * 8 + (sj & 1) * 4;  // in one slot

  const size_t aofs = (size_t)(kg * 512 + wu + fr) * 8;

  floatx4 acc[4][4] = {};  // [ju][jm]
  short8v af[3][4];
  float4 br[3];

  // ---- prologue: slabs 0,1,2 -> regs; write slab 0; A(0), A(1) frags ----
  br[0] = *(const float4*)(bsrc);
  br[1] = *(const float4*)(bsrc + 32);
  br[2] = *(const float4*)(bsrc + 64);
  #pragma unroll
  for (int ju = 0; ju < 4; ++ju) {
    af[0][ju] = *(const short8v*)(w1a + aofs + (size_t)ju * 128);
    af[1][ju] = *(const short8v*)(w1a + 16384 + aofs + (size_t)ju * 128);
  }
  {
    ushort4v q4 = {f2bf(br[0].x), f2bf(br[0].y), f2bf(br[0].z), f2bf(br[0].w)};
    *(ushort4v*)((unsigned short*)&Bs[0][0][0][0] + bofs) = q4;
  }
  step_sync();  // slab 0 visible; br[1],br[2] and A-loads still in flight

  // ---- main loop: 16 steps, one no-drain barrier each ----
  #pragma unroll
  for (int t = 0; t < 16; ++t) {
    const int cur = t & 1;
    const int nxt = cur ^ 1;

    // issue load slab t+3 into reg slot (t+3)%3 (== t%3, freed: slab t is in LDS)
    if (t + 3 < 16)
      br[t % 3] = *(const float4*)(bsrc + (size_t)(t + 3) * 32);
    // prefetch A(t+2) (L2-hot, dist-2)
    if (t + 2 < 16) {
      #pragma unroll
      for (int ju = 0; ju < 4; ++ju)
        af[(t + 2) % 3][ju] =
            *(const short8v*)(w1a + (size_t)(t + 2) * 16384 + aofs + (size_t)ju * 128);
    }
    // cvt + ds_write slab t+1 (its load was issued at step t-2: ~2 steps old)
    if (t + 1 < 16) {
      const float4 bb = br[(t + 1) % 3];
      ushort4v q4 = {f2bf(bb.x), f2bf(bb.y), f2bf(bb.z), f2bf(bb.w)};
      *(ushort4v*)((unsigned short*)&Bs[nxt][0][0][0] + bofs) = q4;
    }

    // 16 MFMA on slab t (Bs[cur]) with A(t) = af[t%3]
    #pragma unroll
    for (int jm = 0; jm < 4; ++jm) {
      const short8v bfv = *(const short8v*)&Bs[cur][kg][jm * 16 + fr][0];
      #pragma unroll
      for (int ju = 0; ju < 4; ++ju)
        acc[ju][jm] = __builtin_amdgcn_mfma_f32_16x16x32_bf16(af[t % 3][ju], bfv, acc[ju][jm], 0, 0, 0);
    }

    if (t < 15) step_sync();  // my ds_write visible; NO vmcnt drain
  }

  // ---- GEMM epilogue: tanh + V-weight; u on the register axis ----
  // C[u][m]: m = jm*16 + fr, u = wu + ju*16 + kg*4 + reg  [verified r7-r17]
  float pm[4] = {0.f, 0.f, 0.f, 0.f};
  #pragma unroll
  for (int ju = 0; ju < 4; ++ju) {
    const float4 qv = *(const float4*)&qv_lds[wu + ju * 16 + kg * 4];
    const float4 vv = *(const float4*)&vv_lds[wu + ju * 16 + kg * 4];
    const float qa[4] = {qv.x, qv.y, qv.z, qv.w};
    const float va[4] = {vv.x, vv.y, vv.z, vv.w};
    #pragma unroll
    for (int jm = 0; jm < 4; ++jm)
      #pragma unroll
      for (int reg = 0; reg < 4; ++reg)
        pm[jm] += fast_tanh(acc[ju][jm][reg] + qa[reg]) * va[reg];
  }
  #pragma unroll
  for (int jm = 0; jm < 4; ++jm) {
    pm[jm] += __shfl_xor(pm[jm], 16, 64);
    pm[jm] += __shfl_xor(pm[jm], 32, 64);
  }
  if (lane < 16) {
    #pragma unroll
    for (int jm = 0; jm < 4; ++jm) part[wid][jm * 16 + lane] = pm[jm];
  }
  __syncthreads();  // full barrier fine here (once)
  if (tid < SBM) {
    float s = 0.f;
    #pragma unroll
    for (int w = 0; w < 8; ++w) s += part[w][tid];
    score[row0 + tid] = s;
    sw[tid] = __expf(s);   // no max-shift: |s| <= ~18, fp32-safe (r16-verified)
  }
  __syncthreads();  // sw visible

  // ---- fused context partial (r16): o = sum_r exp(s_r) * values[r][:] ----
  {
    const int g = tid >> 7;          // 0..3 -> rows g*16..g*16+15
    const int dq = tid & 127;        // d = dq*4
    const float* vrow = values + (size_t)(row0 + g * 16) * DD + dq * 4;
    float4 o4 = {0.f, 0.f, 0.f, 0.f};
    #pragma unroll
    for (int r = 0; r < 16; ++r) {
      const float w = sw[g * 16 + r];
      const float4 v = *(const float4*)(vrow + (size_t)r * DD);  // L2-hot
      o4.x += w * v.x; o4.y += w * v.y; o4.z += w * v.z; o4.w += w * v.w;
    }
    *(float4*)&opart[g][dq * 4] = o4;
  }
  if (wid == 0) {  // wave 0: l = sum of the 64 exp(s)
    float lv = sw[lane];
    #pragma unroll
    for (int m = 1; m < 64; m <<= 1) lv += __shfl_xor(lv, m, 64);
    if (lane == 0) l_part[blockIdx.x] = lv;
  }
  __syncthreads();  // opart visible
  {
    const int d = tid;  // 512 threads = 512 d
    o_part[(size_t)blockIdx.x * DD + d] =
        opart[0][d] + opart[1][d] + opart[2][d] + opart[3][d];
  }
}

// ---------------------------------------------------------------------------
// K3: reduce per-chunk partials -> ctx and Linv. 32 chunks per batch.
// grid (32 b), block 128.
// ---------------------------------------------------------------------------
__global__ __launch_bounds__(128) void reduce_kernel(
    const float* __restrict__ o_part, const float* __restrict__ l_part,
    float* __restrict__ ctx, float* __restrict__ Linv) {
  const int b = blockIdx.x;
  const int d0 = threadIdx.x * 4;
  __shared__ float Ls;
  if (threadIdx.x == 0) {
    float s = 0.f;
    #pragma unroll 8
    for (int c = 0; c < 32; ++c) s += l_part[b * 32 + c];
    Ls = 1.f / s;
    Linv[b] = Ls;
  }
  float4 a = {0.f, 0.f, 0.f, 0.f};
  #pragma unroll 8
  for (int c = 0; c < 32; ++c) {
    const float4 p = *(const float4*)(o_part + (size_t)(b * 32 + c) * DD + d0);
    a.x += p.x; a.y += p.y; a.z += p.z; a.w += p.w;
  }
  __syncthreads();
  const float inv = Ls;
  a.x *= inv; a.y *= inv; a.z *= inv; a.w *= inv;
  *(float4*)(ctx + (size_t)b * DD + d0) = a;
}

// ---------------------------------------------------------------------------
// K4: attn[b,t] = exp(score[b,t]) * Linv[b]. grid 64, block 1024.
// ---------------------------------------------------------------------------
__global__ __launch_bounds__(1024) void attn_kernel(
    const float* __restrict__ score, const float* __restrict__ Linv,
    float* __restrict__ attn) {
  const int i = blockIdx.x * 1024 + threadIdx.x;
  const int b = i >> 11;
  attn[i] = __expf(score[i]) * Linv[b];
}

// ---------------------------------------------------------------------------
extern "C" void kernel_launch(void* const* d_in, const int* in_sizes, int n_in,
                              void* d_out, int out_size, void* d_ws, size_t ws_size,
                              hipStream_t stream) {
  const float* query  = (const float*)d_in[0];
  const float* values = (const float*)d_in[1];
  const float* W1     = (const float*)d_in[2];
  const float* b1     = (const float*)d_in[3];
  const float* W2     = (const float*)d_in[4];
  const float* b2     = (const float*)d_in[5];
  const float* V      = (const float*)d_in[6];
  // d_in[7] = bV: uniform score shift -> softmax-invariant, dropped.

  float* ctx  = (float*)d_out;             // [B,D]
  float* attn = (float*)d_out + BB * DD;   // [B,T,1]

  // ws: qb 64KB | score 256KB | w1a 512KB | o_part 2MB | l_part 4KB | Linv
  float* qb           = (float*)d_ws;                        // [B,U]
  float* score        = qb + BB * UU;                        // [B*T]
  unsigned short* w1a = (unsigned short*)(score + BB * TT);  // 512KB bf16
  float* o_part       = (float*)(w1a + (size_t)UU * DD);     // [1024][512]
  float* l_part       = o_part + (size_t)1024 * DD;          // [1024]
  float* Linv         = l_part + 1024;                       // [32]

  pack_w1a_kernel<<<dim3(16, 4), 256, 0, stream>>>(W1, w1a);
  projq_kernel<<<dim3(BB, UU / 256), 256, 0, stream>>>(query, W2, b2, b1, qb);

  score_fused_kernel<<<(BB * TT) / SBM, 512, 0, stream>>>(
      values, w1a, qb, V, score, o_part, l_part);

  reduce_kernel<<<BB, 128, 0, stream>>>(o_part, l_part, ctx, Linv);
  attn_kernel<<<(BB * TT) / 1024, 1024, 0, stream>>>(score, Linv, attn);
}